// Round 5
// baseline (517.405 us; speedup 1.0000x reference)
//
#include <hip/hip_runtime.h>
#include <math.h>

#define DD 128
#define HH 8
#define BB 256
#define NNODES 2000
#define NSL 16            // slices per batch, one wave each
#define SLEN 125          // 2000/16
#define TANH_CLIPF 10.0f
#define NEG_BIG -1e30f    // finite -inf stand-in (comparator nan-safe; exp underflows to 0)

// workspace layout (float offsets), total 5,101,568 floats ~= 20.4 MB
#define WS_WKP   0          // [128][128]
#define WS_WVP   16384      // [128][128]
#define WS_QH    32768      // [B][8][128]
#define WS_QB    294912     // [B][8]
#define WS_PM    296960     // [B][16][8]
#define WS_PS    329728     // [B][16][8]
#define WS_PACC  362496     // [B][16][8][128]
#define WS_G     4556800    // [B][128]
#define WS_LL    4589568    // [B][2000]

// ---------------- P1: W_kp = wk_i @ w_k ; W_vp = wv_i @ w_v ----------------
__global__ void prep_weights(const float* __restrict__ w_k, const float* __restrict__ w_v,
                             const float* __restrict__ in_proj_w, float* __restrict__ ws) {
    int idx = blockIdx.x * 256 + threadIdx.x;   // 0..32767
    int mat = idx >> 14;
    int e = (idx >> 7) & 127;
    int d = idx & 127;
    const float* A  = in_proj_w + (mat ? 2 * DD * DD : DD * DD) + e * DD;
    const float* Bm = mat ? w_v : w_k;
    float acc = 0.f;
    for (int c = 0; c < DD; ++c) acc += A[c] * Bm[c * DD + d];
    ws[(mat ? WS_WVP : WS_WKP) + e * DD + d] = acc;
}

// ---------------- P2: context -> q0 -> qp -> Qh, qb ----------------
__global__ void prep_query(const float* __restrict__ graph_embed, const float* __restrict__ h_last,
                           const float* __restrict__ h_first, const int* __restrict__ t_ptr,
                           const float* __restrict__ v_l, const float* __restrict__ v_f,
                           const float* __restrict__ w_q, const float* __restrict__ in_proj_w,
                           const float* __restrict__ in_proj_b, float* __restrict__ ws) {
    __shared__ float ctx[3 * DD];
    __shared__ float q0[DD];
    __shared__ float qp[DD];
    int b = blockIdx.x, t = threadIdx.x;
    int t0 = t_ptr[0];
    for (int j = t; j < 3 * DD; j += 128) {
        float v;
        if (j < DD)           v = graph_embed[b * DD + j];
        else if (j < 2 * DD)  v = (t0 == 0) ? v_l[j - DD]     : h_last[b * DD + j - DD];
        else                  v = (t0 == 0) ? v_f[j - 2 * DD] : h_first[b * DD + j - 2 * DD];
        ctx[j] = v;
    }
    __syncthreads();
    {
        float a = 0.f;
        const float* wr = w_q + (size_t)t * 3 * DD;
        for (int j = 0; j < 3 * DD; ++j) a += ctx[j] * wr[j];
        q0[t] = a;
    }
    __syncthreads();
    {
        float a = in_proj_b[t];
        const float* wr = in_proj_w + (size_t)t * DD;
        for (int c = 0; c < DD; ++c) a += q0[c] * wr[c];
        qp[t] = a;
    }
    __syncthreads();
    const float inv = 0.25f;  // 1/sqrt(HD=16)
    float* Qh = ws + WS_QH + (size_t)b * (HH * DD);
    for (int h = 0; h < HH; ++h) {
        float a = 0.f;
        for (int e = 0; e < 16; ++e) a += qp[h * 16 + e] * ws[WS_WKP + (h * 16 + e) * DD + t];
        Qh[h * DD + t] = a * inv;
    }
    if (t < HH) {
        float a = 0.f;
        for (int e = 0; e < 16; ++e) a += qp[t * 16 + e] * in_proj_b[DD + t * 16 + e];
        ws[WS_QB + b * HH + t] = a * inv;
    }
}

// ---------------- Pass A: LDS-free flash attention ----------------
// Lane layout (c = lane>>3, h = lane&7). Lane (c,h) owns the permuted float4 slots
// (j*8+c), j=0..3 of every node row (a bijection on the 32 slots, so Q loads and
// PACC stores use the same formula and downstream layout is natural order).
// Per node: broadcast-read 4 float4s from global (each instr = contiguous 128B,
// 8-way lane-dup; row read once per wave), 16-FMA partial dot, 3 shfl_xor -> full
// score on every lane, per-lane online softmax (h-lanes replicate), accumulate
// from the same registers. Visited handled as two ballot bitmasks (SALU test).
__global__ __launch_bounds__(256, 4) void attn_pass(const float* __restrict__ node,
                                                    const int* __restrict__ visited,
                                                    float* __restrict__ ws) {
    int b    = blockIdx.x >> 2;
    int wq   = blockIdx.x & 3;
    int wave = threadIdx.x >> 6;
    int lane = threadIdx.x & 63;
    int sl   = wq * 4 + wave;
    int n0   = sl * SLEN;
    int c = lane >> 3, h = lane & 7;

    const float* nb = node + (size_t)b * NNODES * DD;

    // Q fragment in permuted slots
    float4 qf0, qf1, qf2, qf3;
    {
        const float* qp = ws + WS_QH + (size_t)b * (HH * DD) + h * DD;
        qf0 = *(const float4*)(qp + (0 * 8 + c) * 4);
        qf1 = *(const float4*)(qp + (1 * 8 + c) * 4);
        qf2 = *(const float4*)(qp + (2 * 8 + c) * 4);
        qf3 = *(const float4*)(qp + (3 * 8 + c) * 4);
    }
    float qb = ws[WS_QB + b * HH + h];

    // visited -> two 64-bit ballot masks (wave-uniform scalars)
    const int* vb = visited + (size_t)b * NNODES;
    int i1 = lane + 64 < SLEN ? lane + 64 : SLEN - 1;
    unsigned long long mask0 = __ballot(vb[n0 + lane] != 0);
    unsigned long long mask1 = __ballot(vb[n0 + i1] != 0);

    float m_h = NEG_BIG, s_h = 0.f;
    float4 a0 = make_float4(0.f, 0.f, 0.f, 0.f), a1 = a0, a2 = a0, a3 = a0;

    // prefetch node 0
    float4 A0, A1, A2, A3;
    {
        const float* rp = nb + (size_t)n0 * DD;
        A0 = *(const float4*)(rp + (0 * 8 + c) * 4);
        A1 = *(const float4*)(rp + (1 * 8 + c) * 4);
        A2 = *(const float4*)(rp + (2 * 8 + c) * 4);
        A3 = *(const float4*)(rp + (3 * 8 + c) * 4);
    }

    for (int n = 0; n < SLEN; ++n) {
        float4 B0 = A0, B1 = A1, B2 = A2, B3 = A3;
        if (n + 1 < SLEN) {
            const float* rp = nb + (size_t)(n0 + n + 1) * DD;
            B0 = *(const float4*)(rp + (0 * 8 + c) * 4);
            B1 = *(const float4*)(rp + (1 * 8 + c) * 4);
            B2 = *(const float4*)(rp + (2 * 8 + c) * 4);
            B3 = *(const float4*)(rp + (3 * 8 + c) * 4);
        }
        // partial dot over this lane's 16 floats
        float part = A0.x*qf0.x + A0.y*qf0.y + A0.z*qf0.z + A0.w*qf0.w
                   + A1.x*qf1.x + A1.y*qf1.y + A1.z*qf1.z + A1.w*qf1.w
                   + A2.x*qf2.x + A2.y*qf2.y + A2.z*qf2.z + A2.w*qf2.w
                   + A3.x*qf3.x + A3.y*qf3.y + A3.z*qf3.z + A3.w*qf3.w;
        part += __shfl_xor(part, 8, 64);
        part += __shfl_xor(part, 16, 64);
        part += __shfl_xor(part, 32, 64);

        bool msk = (((n < 64 ? mask0 : mask1) >> (n & 63)) & 1ULL) != 0;
        float sc = msk ? NEG_BIG : (part + qb);
        float m_new = fmaxf(m_h, sc);
        float p = msk ? 0.f : expf(sc - m_new);
        float scale = expf(m_h - m_new);
        s_h = s_h * scale + p;
        m_h = m_new;
        a0.x = a0.x * scale + p * A0.x; a0.y = a0.y * scale + p * A0.y;
        a0.z = a0.z * scale + p * A0.z; a0.w = a0.w * scale + p * A0.w;
        a1.x = a1.x * scale + p * A1.x; a1.y = a1.y * scale + p * A1.y;
        a1.z = a1.z * scale + p * A1.z; a1.w = a1.w * scale + p * A1.w;
        a2.x = a2.x * scale + p * A2.x; a2.y = a2.y * scale + p * A2.y;
        a2.z = a2.z * scale + p * A2.z; a2.w = a2.w * scale + p * A2.w;
        a3.x = a3.x * scale + p * A3.x; a3.y = a3.y * scale + p * A3.y;
        a3.z = a3.z * scale + p * A3.z; a3.w = a3.w * scale + p * A3.w;

        A0 = B0; A1 = B1; A2 = B2; A3 = B3;
    }

    float* pb = ws + WS_PACC + (size_t)((b * NSL + sl) * HH + h) * DD;
    *(float4*)(pb + (0 * 8 + c) * 4) = a0;
    *(float4*)(pb + (1 * 8 + c) * 4) = a1;
    *(float4*)(pb + (2 * 8 + c) * 4) = a2;
    *(float4*)(pb + (3 * 8 + c) * 4) = a3;
    if (c == 0) {
        ws[WS_PM + (b * NSL + sl) * HH + h] = m_h;
        ws[WS_PS + (b * NSL + sl) * HH + h] = s_h;
    }
}

// ---------------- P3: merge 16 slices -> ctx -> h_c -> g ----------------
__global__ void merge_kernel(const float* __restrict__ in_proj_b, const float* __restrict__ out_w,
                             const float* __restrict__ out_b, const float* __restrict__ w_k,
                             float* __restrict__ ws) {
    __shared__ float cn[HH][132];
    __shared__ float ctxv[DD];
    __shared__ float hc[DD];
    __shared__ float Mh[HH], Sh[HH];
    int b = blockIdx.x, t = threadIdx.x;
    if (t < HH) {
        float M = NEG_BIG;
        for (int i = 0; i < NSL; ++i) M = fmaxf(M, ws[WS_PM + (b * NSL + i) * HH + t]);
        float stot = 0.f;
        for (int i = 0; i < NSL; ++i) {
            float s = ws[WS_PS + (b * NSL + i) * HH + t];
            float m = ws[WS_PM + (b * NSL + i) * HH + t];
            stot += (s > 0.f) ? expf(m - M) * s : 0.f;
        }
        Mh[t] = M; Sh[t] = stot;
    }
    __syncthreads();
    for (int h = 0; h < HH; ++h) {
        float a = 0.f;
        for (int i = 0; i < NSL; ++i) {
            float m = ws[WS_PM + (b * NSL + i) * HH + h];
            float s = ws[WS_PS + (b * NSL + i) * HH + h];
            float w = (s > 0.f) ? expf(m - Mh[h]) : 0.f;
            a += w * ws[WS_PACC + (size_t)((b * NSL + i) * HH + h) * DD + t];
        }
        cn[h][t] = a / Sh[h];
    }
    __syncthreads();
    {
        int h = t >> 4;
        float a = in_proj_b[2 * DD + t];
        const float* wv = ws + WS_WVP + (size_t)t * DD;
        for (int d = 0; d < DD; ++d) a += cn[h][d] * wv[d];
        ctxv[t] = a;
    }
    __syncthreads();
    {
        float a = out_b[t];
        const float* wr = out_w + (size_t)t * DD;
        for (int c = 0; c < DD; ++c) a += ctxv[c] * wr[c];
        hc[t] = a;
    }
    __syncthreads();
    {
        const float invd = 0.08838834764831845f;  // 1/sqrt(128)
        float a = 0.f;
        for (int e = 0; e < DD; ++e) a += hc[e] * w_k[e * DD + t];
        ws[WS_G + b * DD + t] = a * invd;
    }
}

// ---------------- Pass B1: ll[b][n] = masked clip*tanh(node[n].g[b]) ----------------
__global__ __launch_bounds__(256, 8) void logits_ll(const float* __restrict__ node,
                                                    const int* __restrict__ visited,
                                                    float* __restrict__ ws) {
    int b = blockIdx.x >> 3, seg = blockIdx.x & 7;
    int wave = threadIdx.x >> 6, lane = threadIdx.x & 63;
    int r8 = lane >> 3, g = lane & 7;
    int base = seg * 250;
    const float* nb = node + (size_t)b * NNODES * DD;
    float4 g0, g1, g2, g3;
    {
        const float* gp = ws + WS_G + b * DD + g * 16;
        g0 = *(const float4*)(gp + 0); g1 = *(const float4*)(gp + 4);
        g2 = *(const float4*)(gp + 8); g3 = *(const float4*)(gp + 12);
    }
    float4 c0, c1, c2, c3;
    {
        int n = base + wave * 8 + r8;
        const float* p = nb + (size_t)n * DD + g * 16;
        c0 = *(const float4*)(p + 0); c1 = *(const float4*)(p + 4);
        c2 = *(const float4*)(p + 8); c3 = *(const float4*)(p + 12);
    }
    for (int it = 0; it < 8; ++it) {
        int rl = it * 32 + wave * 8 + r8;
        int row = base + rl;
        float4 n0 = c0, n1 = c1, n2 = c2, n3 = c3;
        if (it + 1 < 8) {
            int nr = base + (it + 1) * 32 + wave * 8 + r8;
            if (nr > NNODES - 1) nr = NNODES - 1;
            const float* p = nb + (size_t)nr * DD + g * 16;
            c0 = *(const float4*)(p + 0); c1 = *(const float4*)(p + 4);
            c2 = *(const float4*)(p + 8); c3 = *(const float4*)(p + 12);
        }
        float a = n0.x*g0.x + n0.y*g0.y + n0.z*g0.z + n0.w*g0.w
                + n1.x*g1.x + n1.y*g1.y + n1.z*g1.z + n1.w*g1.w
                + n2.x*g2.x + n2.y*g2.y + n2.z*g2.z + n2.w*g2.w
                + n3.x*g3.x + n3.y*g3.y + n3.z*g3.z + n3.w*g3.w;
        a += __shfl_xor(a, 1, 64);
        a += __shfl_xor(a, 2, 64);
        a += __shfl_xor(a, 4, 64);
        float val = TANH_CLIPF * tanhf(a);
        if (g == 0 && rl < 250) {
            if (visited[(size_t)b * NNODES + row]) val = NEG_BIG;
            ws[WS_LL + (size_t)b * NNODES + row] = val;
        }
    }
}

// ---------------- Pass B2: per-batch softmax over ll -> probs + logits ----------------
__global__ __launch_bounds__(256, 4) void softmax_out(const float* __restrict__ ws,
                                                      float* __restrict__ out) {
    __shared__ float red[4];
    int b = blockIdx.x, t = threadIdx.x;
    const float* ll = ws + WS_LL + (size_t)b * NNODES;
    float v0[8];
#pragma unroll
    for (int j = 0; j < 8; ++j) {
        int idx = j * 256 + t;
        v0[j] = (idx < NNODES) ? ll[idx] : NEG_BIG;
    }
    float mx = v0[0];
#pragma unroll
    for (int j = 1; j < 8; ++j) mx = fmaxf(mx, v0[j]);
    for (int m = 1; m <= 32; m <<= 1) mx = fmaxf(mx, __shfl_xor(mx, m, 64));
    int wv = t >> 6;
    if ((t & 63) == 0) red[wv] = mx;
    __syncthreads();
    float M = fmaxf(fmaxf(red[0], red[1]), fmaxf(red[2], red[3]));
    __syncthreads();
    float e[8]; float sm = 0.f;
#pragma unroll
    for (int j = 0; j < 8; ++j) { e[j] = expf(v0[j] - M); sm += e[j]; }
    for (int m = 1; m <= 32; m <<= 1) sm += __shfl_xor(sm, m, 64);
    if ((t & 63) == 0) red[wv] = sm;
    __syncthreads();
    float inv = 1.0f / (red[0] + red[1] + red[2] + red[3]);
#pragma unroll
    for (int j = 0; j < 8; ++j) {
        int idx = j * 256 + t;
        if (idx < NNODES) {
            out[(size_t)b * NNODES + idx] = e[j] * inv;
            out[(size_t)BB * NNODES + (size_t)b * NNODES + idx] = v0[j];
        }
    }
}

extern "C" void kernel_launch(void* const* d_in, const int* in_sizes, int n_in,
                              void* d_out, int out_size, void* d_ws, size_t ws_size,
                              hipStream_t stream) {
    const float* node        = (const float*)d_in[0];
    const float* graph_embed = (const float*)d_in[1];
    const float* h_last      = (const float*)d_in[2];
    const float* h_first     = (const float*)d_in[3];
    const int*   visited     = (const int*)d_in[4];
    const int*   t_ptr       = (const int*)d_in[5];
    const float* v_l         = (const float*)d_in[6];
    const float* v_f         = (const float*)d_in[7];
    const float* w_q         = (const float*)d_in[8];
    const float* w_k         = (const float*)d_in[9];
    const float* w_v         = (const float*)d_in[10];
    const float* in_proj_w   = (const float*)d_in[11];
    const float* in_proj_b   = (const float*)d_in[12];
    const float* out_w       = (const float*)d_in[13];
    const float* out_b       = (const float*)d_in[14];
    float* out = (float*)d_out;
    float* ws  = (float*)d_ws;

    prep_weights<<<128, 256, 0, stream>>>(w_k, w_v, in_proj_w, ws);
    prep_query<<<BB, 128, 0, stream>>>(graph_embed, h_last, h_first, t_ptr, v_l, v_f,
                                       w_q, in_proj_w, in_proj_b, ws);
    attn_pass<<<BB * 4, 256, 0, stream>>>(node, visited, ws);
    merge_kernel<<<BB, 128, 0, stream>>>(in_proj_b, out_w, out_b, w_k, ws);
    logits_ll<<<BB * 8, 256, 0, stream>>>(node, visited, ws);
    softmax_out<<<BB, 256, 0, stream>>>(ws, out);
}

// Round 7
// 513.308 us; speedup vs baseline: 1.0080x; 1.0080x over previous
//
#include <hip/hip_runtime.h>
#include <math.h>

#define DD 128
#define HH 8
#define BB 256
#define NNODES 2000
#define NSL 16            // slices per batch, one wave each
#define SLEN 125          // 2000/16
#define TANH_CLIPF 10.0f
#define NEG_BIG -1e30f    // finite -inf stand-in (comparator nan-safe; exp underflows to 0)

// workspace layout (float offsets), total 5,101,568 floats ~= 20.4 MB
#define WS_WKP   0          // [128][128]
#define WS_WVP   16384      // [128][128]
#define WS_QH    32768      // [B][8][128]
#define WS_QB    294912     // [B][8]
#define WS_PM    296960     // [B][16][8]
#define WS_PS    329728     // [B][16][8]
#define WS_PACC  362496     // [B][16][8][128]
#define WS_G     4556800    // [B][128]
#define WS_LL    4589568    // [B][2000]

// ---------------- P1: W_kp = wk_i @ w_k ; W_vp = wv_i @ w_v ----------------
__global__ void prep_weights(const float* __restrict__ w_k, const float* __restrict__ w_v,
                             const float* __restrict__ in_proj_w, float* __restrict__ ws) {
    int idx = blockIdx.x * 256 + threadIdx.x;   // 0..32767
    int mat = idx >> 14;
    int e = (idx >> 7) & 127;
    int d = idx & 127;
    const float* A  = in_proj_w + (mat ? 2 * DD * DD : DD * DD) + e * DD;
    const float* Bm = mat ? w_v : w_k;
    float acc = 0.f;
    for (int c = 0; c < DD; ++c) acc += A[c] * Bm[c * DD + d];
    ws[(mat ? WS_WVP : WS_WKP) + e * DD + d] = acc;
}

// ---------------- P2: context -> q0 -> qp -> Qh, qb ----------------
__global__ void prep_query(const float* __restrict__ graph_embed, const float* __restrict__ h_last,
                           const float* __restrict__ h_first, const int* __restrict__ t_ptr,
                           const float* __restrict__ v_l, const float* __restrict__ v_f,
                           const float* __restrict__ w_q, const float* __restrict__ in_proj_w,
                           const float* __restrict__ in_proj_b, float* __restrict__ ws) {
    __shared__ float ctx[3 * DD];
    __shared__ float q0[DD];
    __shared__ float qp[DD];
    int b = blockIdx.x, t = threadIdx.x;
    int t0 = t_ptr[0];
    for (int j = t; j < 3 * DD; j += 128) {
        float v;
        if (j < DD)           v = graph_embed[b * DD + j];
        else if (j < 2 * DD)  v = (t0 == 0) ? v_l[j - DD]     : h_last[b * DD + j - DD];
        else                  v = (t0 == 0) ? v_f[j - 2 * DD] : h_first[b * DD + j - 2 * DD];
        ctx[j] = v;
    }
    __syncthreads();
    {
        float a = 0.f;
        const float* wr = w_q + (size_t)t * 3 * DD;
        for (int j = 0; j < 3 * DD; ++j) a += ctx[j] * wr[j];
        q0[t] = a;
    }
    __syncthreads();
    {
        float a = in_proj_b[t];
        const float* wr = in_proj_w + (size_t)t * DD;
        for (int c = 0; c < DD; ++c) a += q0[c] * wr[c];
        qp[t] = a;
    }
    __syncthreads();
    const float inv = 0.25f;  // 1/sqrt(HD=16)
    float* Qh = ws + WS_QH + (size_t)b * (HH * DD);
    for (int h = 0; h < HH; ++h) {
        float a = 0.f;
        for (int e = 0; e < 16; ++e) a += qp[h * 16 + e] * ws[WS_WKP + (h * 16 + e) * DD + t];
        Qh[h * DD + t] = a * inv;
    }
    if (t < HH) {
        float a = 0.f;
        for (int e = 0; e < 16; ++e) a += qp[t * 16 + e] * in_proj_b[DD + t * 16 + e];
        ws[WS_QB + b * HH + t] = a * inv;
    }
}

// ---------------- Pass A: LDS-free flash attention, 2-node pipeline ----------------
// Lane layout (c = lane>>3, h = lane&7). Lane (c,h) owns permuted float4 slots (j*8+c).
// Per pair of nodes: prefetch next pair (8 loads, 1KB/wave in flight), two independent
// 16-FMA dots (ILP x2), 3 shfl_xor each, per-lane online softmax with __expf (2 instr
// vs ~25 for OCML expf), accumulate from the load registers. 125 nodes padded to 126;
// node 125 masked via uniform n>=SLEN test.
__global__ __launch_bounds__(256, 4) void attn_pass(const float* __restrict__ node,
                                                    const int* __restrict__ visited,
                                                    float* __restrict__ ws) {
    int b    = blockIdx.x >> 2;
    int wq   = blockIdx.x & 3;
    int wave = threadIdx.x >> 6;
    int lane = threadIdx.x & 63;
    int sl   = wq * 4 + wave;
    int n0   = sl * SLEN;
    int c = lane >> 3, h = lane & 7;

    const float* nb = node + (size_t)b * NNODES * DD;

    float4 qf0, qf1, qf2, qf3;
    {
        const float* qp = ws + WS_QH + (size_t)b * (HH * DD) + h * DD;
        qf0 = *(const float4*)(qp + (0 * 8 + c) * 4);
        qf1 = *(const float4*)(qp + (1 * 8 + c) * 4);
        qf2 = *(const float4*)(qp + (2 * 8 + c) * 4);
        qf3 = *(const float4*)(qp + (3 * 8 + c) * 4);
    }
    float qb = ws[WS_QB + b * HH + h];

    // visited -> two 64-bit ballot masks (wave-uniform)
    const int* vb = visited + (size_t)b * NNODES;
    int i1 = lane + 64 < SLEN ? lane + 64 : SLEN - 1;
    unsigned long long mask0 = __ballot(vb[n0 + lane] != 0);
    unsigned long long mask1 = __ballot(vb[n0 + i1] != 0);

    float m_h = NEG_BIG, s_h = 0.f;
    float4 a0 = make_float4(0.f, 0.f, 0.f, 0.f), a1 = a0, a2 = a0, a3 = a0;

#define LOADROW(P0, P1, P2, P3, nidx) { \
        int nn_ = n0 + (nidx); if (nn_ > NNODES - 1) nn_ = NNODES - 1; \
        const float* rp_ = nb + (size_t)nn_ * DD; \
        P0 = *(const float4*)(rp_ + (0 * 8 + c) * 4); \
        P1 = *(const float4*)(rp_ + (1 * 8 + c) * 4); \
        P2 = *(const float4*)(rp_ + (2 * 8 + c) * 4); \
        P3 = *(const float4*)(rp_ + (3 * 8 + c) * 4); }

    float4 A0, A1, A2, A3, A4, A5, A6, A7;   // current pair
    float4 B0, B1, B2, B3, B4, B5, B6, B7;   // next pair
    LOADROW(A0, A1, A2, A3, 0)
    LOADROW(A4, A5, A6, A7, 1)

    const int NPAIR = 63;   // 126 node slots (last one masked)
    for (int i = 0; i < NPAIR; ++i) {
        if (i + 1 < NPAIR) {
            LOADROW(B0, B1, B2, B3, 2 * i + 2)
            LOADROW(B4, B5, B6, B7, 2 * i + 3)
        }
        // two independent dots (ILP)
        float pa = A0.x*qf0.x + A0.y*qf0.y + A0.z*qf0.z + A0.w*qf0.w
                 + A1.x*qf1.x + A1.y*qf1.y + A1.z*qf1.z + A1.w*qf1.w
                 + A2.x*qf2.x + A2.y*qf2.y + A2.z*qf2.z + A2.w*qf2.w
                 + A3.x*qf3.x + A3.y*qf3.y + A3.z*qf3.z + A3.w*qf3.w;
        float pb2 = A4.x*qf0.x + A4.y*qf0.y + A4.z*qf0.z + A4.w*qf0.w
                  + A5.x*qf1.x + A5.y*qf1.y + A5.z*qf1.z + A5.w*qf1.w
                  + A6.x*qf2.x + A6.y*qf2.y + A6.z*qf2.z + A6.w*qf2.w
                  + A7.x*qf3.x + A7.y*qf3.y + A7.z*qf3.z + A7.w*qf3.w;
        pa  += __shfl_xor(pa, 8, 64);   pb2 += __shfl_xor(pb2, 8, 64);
        pa  += __shfl_xor(pa, 16, 64);  pb2 += __shfl_xor(pb2, 16, 64);
        pa  += __shfl_xor(pa, 32, 64);  pb2 += __shfl_xor(pb2, 32, 64);

        int na = 2 * i, nbx = 2 * i + 1;
        bool mska = (na >= SLEN)  || ((((na  < 64 ? mask0 : mask1) >> (na  & 63)) & 1ULL) != 0);
        bool mskb = (nbx >= SLEN) || ((((nbx < 64 ? mask0 : mask1) >> (nbx & 63)) & 1ULL) != 0);
        float sa = mska ? NEG_BIG : (pa + qb);
        float sb = mskb ? NEG_BIG : (pb2 + qb);

        // joint online-softmax update for the pair
        float m_new = fmaxf(m_h, fmaxf(sa, sb));
        float ea = mska ? 0.f : __expf(sa - m_new);
        float eb = mskb ? 0.f : __expf(sb - m_new);
        float scale = __expf(m_h - m_new);
        s_h = s_h * scale + ea + eb;
        m_h = m_new;
        a0.x = a0.x * scale + ea * A0.x + eb * A4.x;
        a0.y = a0.y * scale + ea * A0.y + eb * A4.y;
        a0.z = a0.z * scale + ea * A0.z + eb * A4.z;
        a0.w = a0.w * scale + ea * A0.w + eb * A4.w;
        a1.x = a1.x * scale + ea * A1.x + eb * A5.x;
        a1.y = a1.y * scale + ea * A1.y + eb * A5.y;
        a1.z = a1.z * scale + ea * A1.z + eb * A5.z;
        a1.w = a1.w * scale + ea * A1.w + eb * A5.w;
        a2.x = a2.x * scale + ea * A2.x + eb * A6.x;
        a2.y = a2.y * scale + ea * A2.y + eb * A6.y;
        a2.z = a2.z * scale + ea * A2.z + eb * A6.z;
        a2.w = a2.w * scale + ea * A2.w + eb * A6.w;
        a3.x = a3.x * scale + ea * A3.x + eb * A7.x;
        a3.y = a3.y * scale + ea * A3.y + eb * A7.y;
        a3.z = a3.z * scale + ea * A3.z + eb * A7.z;
        a3.w = a3.w * scale + ea * A3.w + eb * A7.w;

        A0 = B0; A1 = B1; A2 = B2; A3 = B3;
        A4 = B4; A5 = B5; A6 = B6; A7 = B7;
    }
#undef LOADROW

    float* pb = ws + WS_PACC + (size_t)((b * NSL + sl) * HH + h) * DD;
    *(float4*)(pb + (0 * 8 + c) * 4) = a0;
    *(float4*)(pb + (1 * 8 + c) * 4) = a1;
    *(float4*)(pb + (2 * 8 + c) * 4) = a2;
    *(float4*)(pb + (3 * 8 + c) * 4) = a3;
    if (c == 0) {
        ws[WS_PM + (b * NSL + sl) * HH + h] = m_h;
        ws[WS_PS + (b * NSL + sl) * HH + h] = s_h;
    }
}

// ---------------- P3: merge 16 slices -> ctx -> h_c -> g ----------------
__global__ void merge_kernel(const float* __restrict__ in_proj_b, const float* __restrict__ out_w,
                             const float* __restrict__ out_b, const float* __restrict__ w_k,
                             float* __restrict__ ws) {
    __shared__ float cn[HH][132];
    __shared__ float ctxv[DD];
    __shared__ float hc[DD];
    __shared__ float Mh[HH], Sh[HH];
    int b = blockIdx.x, t = threadIdx.x;
    if (t < HH) {
        float M = NEG_BIG;
        for (int i = 0; i < NSL; ++i) M = fmaxf(M, ws[WS_PM + (b * NSL + i) * HH + t]);
        float stot = 0.f;
        for (int i = 0; i < NSL; ++i) {
            float s = ws[WS_PS + (b * NSL + i) * HH + t];
            float m = ws[WS_PM + (b * NSL + i) * HH + t];
            stot += (s > 0.f) ? expf(m - M) * s : 0.f;
        }
        Mh[t] = M; Sh[t] = stot;
    }
    __syncthreads();
    for (int h = 0; h < HH; ++h) {
        float a = 0.f;
        for (int i = 0; i < NSL; ++i) {
            float m = ws[WS_PM + (b * NSL + i) * HH + h];
            float s = ws[WS_PS + (b * NSL + i) * HH + h];
            float w = (s > 0.f) ? expf(m - Mh[h]) : 0.f;
            a += w * ws[WS_PACC + (size_t)((b * NSL + i) * HH + h) * DD + t];
        }
        cn[h][t] = a / Sh[h];
    }
    __syncthreads();
    {
        int h = t >> 4;
        float a = in_proj_b[2 * DD + t];
        const float* wv = ws + WS_WVP + (size_t)t * DD;
        for (int d = 0; d < DD; ++d) a += cn[h][d] * wv[d];
        ctxv[t] = a;
    }
    __syncthreads();
    {
        float a = out_b[t];
        const float* wr = out_w + (size_t)t * DD;
        for (int c = 0; c < DD; ++c) a += ctxv[c] * wr[c];
        hc[t] = a;
    }
    __syncthreads();
    {
        const float invd = 0.08838834764831845f;  // 1/sqrt(128)
        float a = 0.f;
        for (int e = 0; e < DD; ++e) a += hc[e] * w_k[e * DD + t];
        ws[WS_G + b * DD + t] = a * invd;
    }
}

// ---------------- Pass B1: ll[b][n] = masked clip*tanh(node[n].g[b]) ----------------
// Batch order REVERSED vs attn_pass: attn streams node[0..255] ascending, so the tail
// batches are L3-resident when this kernel starts; reading them first converts HBM
// fetch into L3 hits.
__global__ __launch_bounds__(256, 8) void logits_ll(const float* __restrict__ node,
                                                    const int* __restrict__ visited,
                                                    float* __restrict__ ws) {
    int b = (BB - 1) - (blockIdx.x >> 3), seg = blockIdx.x & 7;
    int wave = threadIdx.x >> 6, lane = threadIdx.x & 63;
    int r8 = lane >> 3, g = lane & 7;
    int base = seg * 250;
    const float* nb = node + (size_t)b * NNODES * DD;
    float4 g0, g1, g2, g3;
    {
        const float* gp = ws + WS_G + b * DD + g * 16;
        g0 = *(const float4*)(gp + 0); g1 = *(const float4*)(gp + 4);
        g2 = *(const float4*)(gp + 8); g3 = *(const float4*)(gp + 12);
    }
    float4 c0, c1, c2, c3;
    {
        int n = base + wave * 8 + r8;
        const float* p = nb + (size_t)n * DD + g * 16;
        c0 = *(const float4*)(p + 0); c1 = *(const float4*)(p + 4);
        c2 = *(const float4*)(p + 8); c3 = *(const float4*)(p + 12);
    }
    for (int it = 0; it < 8; ++it) {
        int rl = it * 32 + wave * 8 + r8;
        int row = base + rl;
        float4 n0 = c0, n1 = c1, n2 = c2, n3 = c3;
        if (it + 1 < 8) {
            int nr = base + (it + 1) * 32 + wave * 8 + r8;
            if (nr > NNODES - 1) nr = NNODES - 1;
            const float* p = nb + (size_t)nr * DD + g * 16;
            c0 = *(const float4*)(p + 0); c1 = *(const float4*)(p + 4);
            c2 = *(const float4*)(p + 8); c3 = *(const float4*)(p + 12);
        }
        float a = n0.x*g0.x + n0.y*g0.y + n0.z*g0.z + n0.w*g0.w
                + n1.x*g1.x + n1.y*g1.y + n1.z*g1.z + n1.w*g1.w
                + n2.x*g2.x + n2.y*g2.y + n2.z*g2.z + n2.w*g2.w
                + n3.x*g3.x + n3.y*g3.y + n3.z*g3.z + n3.w*g3.w;
        a += __shfl_xor(a, 1, 64);
        a += __shfl_xor(a, 2, 64);
        a += __shfl_xor(a, 4, 64);
        float val = TANH_CLIPF * tanhf(a);
        if (g == 0 && rl < 250) {
            if (visited[(size_t)b * NNODES + row]) val = NEG_BIG;
            ws[WS_LL + (size_t)b * NNODES + row] = val;
        }
    }
}

// ---------------- Pass B2: per-batch softmax over ll -> probs + logits ----------------
__global__ __launch_bounds__(256, 4) void softmax_out(const float* __restrict__ ws,
                                                      float* __restrict__ out) {
    __shared__ float red[4];
    int b = blockIdx.x, t = threadIdx.x;
    const float* ll = ws + WS_LL + (size_t)b * NNODES;
    float v0[8];
#pragma unroll
    for (int j = 0; j < 8; ++j) {
        int idx = j * 256 + t;
        v0[j] = (idx < NNODES) ? ll[idx] : NEG_BIG;
    }
    float mx = v0[0];
#pragma unroll
    for (int j = 1; j < 8; ++j) mx = fmaxf(mx, v0[j]);
    for (int m = 1; m <= 32; m <<= 1) mx = fmaxf(mx, __shfl_xor(mx, m, 64));
    int wv = t >> 6;
    if ((t & 63) == 0) red[wv] = mx;
    __syncthreads();
    float M = fmaxf(fmaxf(red[0], red[1]), fmaxf(red[2], red[3]));
    __syncthreads();
    float e[8]; float sm = 0.f;
#pragma unroll
    for (int j = 0; j < 8; ++j) { e[j] = expf(v0[j] - M); sm += e[j]; }
    for (int m = 1; m <= 32; m <<= 1) sm += __shfl_xor(sm, m, 64);
    if ((t & 63) == 0) red[wv] = sm;
    __syncthreads();
    float inv = 1.0f / (red[0] + red[1] + red[2] + red[3]);
#pragma unroll
    for (int j = 0; j < 8; ++j) {
        int idx = j * 256 + t;
        if (idx < NNODES) {
            out[(size_t)b * NNODES + idx] = e[j] * inv;
            out[(size_t)BB * NNODES + (size_t)b * NNODES + idx] = v0[j];
        }
    }
}

extern "C" void kernel_launch(void* const* d_in, const int* in_sizes, int n_in,
                              void* d_out, int out_size, void* d_ws, size_t ws_size,
                              hipStream_t stream) {
    const float* node        = (const float*)d_in[0];
    const float* graph_embed = (const float*)d_in[1];
    const float* h_last      = (const float*)d_in[2];
    const float* h_first     = (const float*)d_in[3];
    const int*   visited     = (const int*)d_in[4];
    const int*   t_ptr       = (const int*)d_in[5];
    const float* v_l         = (const float*)d_in[6];
    const float* v_f         = (const float*)d_in[7];
    const float* w_q         = (const float*)d_in[8];
    const float* w_k         = (const float*)d_in[9];
    const float* w_v         = (const float*)d_in[10];
    const float* in_proj_w   = (const float*)d_in[11];
    const float* in_proj_b   = (const float*)d_in[12];
    const float* out_w       = (const float*)d_in[13];
    const float* out_b       = (const float*)d_in[14];
    float* out = (float*)d_out;
    float* ws  = (float*)d_ws;

    prep_weights<<<128, 256, 0, stream>>>(w_k, w_v, in_proj_w, ws);
    prep_query<<<BB, 128, 0, stream>>>(graph_embed, h_last, h_first, t_ptr, v_l, v_f,
                                       w_q, in_proj_w, in_proj_b, ws);
    attn_pass<<<BB * 4, 256, 0, stream>>>(node, visited, ws);
    merge_kernel<<<BB, 128, 0, stream>>>(in_proj_b, out_w, out_b, w_k, ws);
    logits_ll<<<BB * 8, 256, 0, stream>>>(node, visited, ws);
    softmax_out<<<BB, 256, 0, stream>>>(ws, out);
}